// Round 4
// baseline (1537.888 us; speedup 1.0000x reference)
//
#include <hip/hip_runtime.h>
#include <hip/hip_bf16.h>

typedef unsigned short u16;
typedef __attribute__((ext_vector_type(4))) unsigned short u16x4;

#define CH 64
#define HH 256
#define WW 256
#define HW (HH*WW)
#define CHW (CH*HW)

#define TH 8
#define TW 16
#define XH 12
#define XW 20
#define NX (XH*XW)   // 240 halo pixels (attention inputs for the out1 grid)
#define OH 10
#define OW 18
#define NO (OH*OW)   // 180 out1 pixels (conv tile + halo)
#define XS 68        // LDS row stride (u16): 136 B -> 8B-aligned vec4 reads

__device__ __forceinline__ float b2f(u16 u) {
    return __uint_as_float(((unsigned)u) << 16);
}
__device__ __forceinline__ u16 f2b(float f) {
    __hip_bfloat16 h = __float2bfloat16(f);
    u16 r; __builtin_memcpy(&r, &h, 2); return r;
}

__global__ __launch_bounds__(256) void fused_kernel(
    const float* __restrict__ x, const float* __restrict__ wqkv,
    const float* __restrict__ bqkv, const float* __restrict__ wmlp,
    float* __restrict__ out)
{
    // single buffer, serially holds: k -> v -> out1 (bf16).  32640 B
    __shared__ __align__(16) u16 kvs[NX*XS];

    const int t   = threadIdx.x;
    const int b   = blockIdx.z;
    const int gy0 = blockIdx.y * TH;
    const int gx0 = blockIdx.x * TW;
    const float* xb = x + (size_t)b * CHW;

    // halo-pixel coords (valid for t < NX)
    const int hy = t / XW, hx = t % XW;
    const int hgy = gy0 - 2 + hy, hgx = gx0 - 2 + hx;
    const bool hin = ((unsigned)hgy < HH) && ((unsigned)hgx < WW);

    // ---- stage 1: k for all 240 halo pixels (OOB -> 0: reference zero-pads
    //      the patch gather AFTER the biased 1x1 conv)
    if (t < NX) {
        if (hin) {
            float xr[CH];
            const float* xp = xb + hgy*WW + hgx;
            #pragma unroll
            for (int c = 0; c < CH; ++c) xr[c] = xp[c*HW];
            for (int o = 0; o < CH; ++o) {
                float a = bqkv[CH + o];
                const float* wr = wqkv + (size_t)(CH + o)*CH;
                #pragma unroll
                for (int c = 0; c < CH; ++c) a += xr[c] * wr[c];
                kvs[t*XS + o] = f2b(a);
            }
        } else {
            for (int o = 0; o < CH; ++o) kvs[t*XS + o] = 0;
        }
    }
    __syncthreads();

    // ---- stage 2: q (register-chunked) fused with 9 dots -> softmax
    const int oy = t / OW, ox = t % OW;               // out1 coords (t < NO)
    const int ogy = gy0 - 1 + oy, ogx = gx0 - 1 + ox;
    const bool oin = ((unsigned)ogy < HH) && ((unsigned)ogx < WW);
    int kp[9];
    float attn[9];
    if (t < NO) {
        int xp0 = (oy + 1)*XW + (ox + 1);
        #pragma unroll
        for (int n = 0; n < 9; ++n) kp[n] = xp0 + (n/3 - 1)*XW + (n%3 - 1);
        if (oin) {
            float xq[CH];
            const float* xp = xb + ogy*WW + ogx;
            #pragma unroll
            for (int c = 0; c < CH; ++c) xq[c] = xp[c*HW];
            float dots[9];
            #pragma unroll
            for (int n = 0; n < 9; ++n) dots[n] = 0.f;
            for (int oc = 0; oc < 16; ++oc) {         // 4 q-channels per iter
                float q4[4];
                #pragma unroll
                for (int j = 0; j < 4; ++j) {
                    int o = oc*4 + j;
                    float a = bqkv[o];
                    const float* wr = wqkv + (size_t)o*CH;
                    #pragma unroll
                    for (int c = 0; c < CH; ++c) a += xq[c] * wr[c];
                    q4[j] = a;
                }
                #pragma unroll
                for (int n = 0; n < 9; ++n) {
                    u16x4 k4 = *(const u16x4*)&kvs[kp[n]*XS + oc*4];
                    #pragma unroll
                    for (int j = 0; j < 4; ++j) dots[n] += q4[j] * b2f(k4[j]);
                }
            }
            float mx = -1e30f;
            #pragma unroll
            for (int n = 0; n < 9; ++n) { dots[n] *= 0.125f; mx = fmaxf(mx, dots[n]); }
            float se = 0.f;
            #pragma unroll
            for (int n = 0; n < 9; ++n) { attn[n] = __expf(dots[n] - mx); se += attn[n]; }
            float inv = 1.f / se;
            #pragma unroll
            for (int n = 0; n < 9; ++n) attn[n] *= inv;
        }
    }
    __syncthreads();   // all k reads done before overwriting with v

    // ---- stage 3: v for all 240 halo pixels (overwrites k)
    if (t < NX) {
        if (hin) {
            float xr[CH];
            const float* xp = xb + hgy*WW + hgx;
            #pragma unroll
            for (int c = 0; c < CH; ++c) xr[c] = xp[c*HW];
            for (int o = 0; o < CH; ++o) {
                float a = bqkv[2*CH + o];
                const float* wr = wqkv + (size_t)(2*CH + o)*CH;
                #pragma unroll
                for (int c = 0; c < CH; ++c) a += xr[c] * wr[c];
                kvs[t*XS + o] = f2b(a);
            }
        } else {
            for (int o = 0; o < CH; ++o) kvs[t*XS + o] = 0;
        }
    }
    __syncthreads();

    // ---- stage 4: out1 = x + attn.v  (0 at image-OOB == conv zero-pad)
    float o1[CH];
    if (t < NO) {
        if (oin) {
            const float* xp = xb + ogy*WW + ogx;
            #pragma unroll
            for (int c = 0; c < CH; ++c) o1[c] = xp[c*HW];   // residual
            #pragma unroll
            for (int n = 0; n < 9; ++n) {
                float an = attn[n];
                const int base = kp[n]*XS;
                #pragma unroll
                for (int cg = 0; cg < 16; ++cg) {
                    u16x4 v4 = *(const u16x4*)&kvs[base + cg*4];
                    #pragma unroll
                    for (int j = 0; j < 4; ++j) o1[cg*4+j] += an * b2f(v4[j]);
                }
            }
        } else {
            #pragma unroll
            for (int c = 0; c < CH; ++c) o1[c] = 0.f;
        }
    }
    __syncthreads();   // ALL v reads done before out1 overwrites rows 0..179
    if (t < NO) {
        #pragma unroll
        for (int c = 0; c < CH; ++c) kvs[t*XS + c] = f2b(o1[c]);
    }
    __syncthreads();

    // ---- stage 5: 3x3 conv (64->64) + ReLU; 128 px x 2 channel-halves
    {
        const int hpx = t & 127, hf = t >> 7;          // wave-uniform hf
        const int ty = hpx / TW, tx = hpx % TW;
        const int obase = (ty + 1)*OW + (tx + 1);
        float acc[32];
        #pragma unroll
        for (int o = 0; o < 32; ++o) acc[o] = 0.f;
        const float* wb = wmlp + (size_t)(hf*32)*576;   // [o][ci][3][3]
        for (int n = 0; n < 9; ++n) {
            int opix = obase + (n/3 - 1)*OW + (n%3 - 1);
            for (int cg = 0; cg < 16; ++cg) {
                u16x4 a4 = *(const u16x4*)&kvs[opix*XS + cg*4];
                #pragma unroll
                for (int j = 0; j < 4; ++j) {
                    float a = b2f(a4[j]);
                    const float* wr = wb + (cg*4 + j)*9 + n;   // wave-uniform
                    #pragma unroll
                    for (int o = 0; o < 32; ++o)
                        acc[o] += a * wr[o*576];
                }
            }
        }
        float* op = out + (size_t)b*CHW + (size_t)(hf*32)*HW + (gy0 + ty)*WW + (gx0 + tx);
        #pragma unroll
        for (int o = 0; o < 32; ++o)
            op[o*HW] = fmaxf(acc[o], 0.f);
    }
}

extern "C" void kernel_launch(void* const* d_in, const int* in_sizes, int n_in,
                              void* d_out, int out_size, void* d_ws, size_t ws_size,
                              hipStream_t stream) {
    const float* x    = (const float*)d_in[0];
    const float* wqkv = (const float*)d_in[1];
    const float* bqkv = (const float*)d_in[2];
    const float* wmlp = (const float*)d_in[3];
    float* outp = (float*)d_out;

    dim3 grid(WW/TW, HH/TH, 4);
    fused_kernel<<<grid, 256, 0, stream>>>(x, wqkv, bqkv, wmlp, outp);
}